// Round 8
// baseline (717.934 us; speedup 1.0000x reference)
//
#include <hip/hip_runtime.h>

// DeepSeek-V2 expert MLP, fp8-block-dequant weights. T=8192, H=5120, F=1536.
// Round-8: R7 flatmm data paths (B fragment-major global->VGPR, A glds->LDS
// with verified XOR swizzle, prep/epilogue byte-identical) with the K-loop
// restructured into 64-K SUPER-steps:
//   * one VMBAR(4) s_barrier per 64-K (was per 32-K): queue at top of super t
//     = [A(t)4, B(t,a)4, B(t,b)4, A(t+1)4] -> wait-to-4 drains A(t),B(t).
//   * A slot = 16 KB (two 8-KB half-slabs, same verified subtile layout),
//     ring-3 = 48 KB LDS.
//   * fragment ds_reads software-pipelined with COUNTED lgkmcnt(4/0): only
//     one exposed LDS latency per 64-K (was four), next-half reads issued
//     under the running MFMA16 (311 cyc).
//   * B double-banked bgA/bgB = the two 32-K halves of each super; reload
//     after last consuming MFMA (WAR via reg dataflow, R7-verified pattern).
// Cycle model: 32 MFMA/kslice/wave = 621 cyc/SIMD (19.4 cyc ea, m06);
// R7 period ~1700-2800 -> MfmaUtil 41%. This cuts fixed cost to ~330/64-K.

typedef __bf16 bf16x8 __attribute__((ext_vector_type(8)));
typedef float  f32x4  __attribute__((ext_vector_type(4)));
typedef unsigned int u32x4 __attribute__((ext_vector_type(4)));

__device__ __forceinline__ void glds16(const __bf16* g, __bf16* l) {
  __builtin_amdgcn_global_load_lds(
      (const __attribute__((address_space(1))) void*)g,
      (__attribute__((address_space(3))) void*)l, 16, 0, 0);
}

// A-side inverse swizzle (R4-verified pair with laneoff below; 0 conflicts).
__device__ __forceinline__ void chunk_rk(int c, int& row, int& k) {
  int s = c >> 6;
  int w = (c & 63) << 4;
  int wl = w ^ (((w >> 9) & 1) << 5) ^ (((w >> 7) & 1) << 4);
  row = (s << 4) + (wl >> 6);
  k = (wl & 63) >> 1;
}

#define LGKMC(n)                                              \
  do {                                                        \
    asm volatile("s_waitcnt lgkmcnt(" #n ")" ::: "memory");   \
    __builtin_amdgcn_sched_barrier(0);                        \
  } while (0)

#define VMBAR(n)                                                       \
  do {                                                                 \
    __builtin_amdgcn_sched_barrier(0);                                 \
    asm volatile("s_waitcnt vmcnt(" #n ")\n\ts_barrier" ::: "memory"); \
    __builtin_amdgcn_sched_barrier(0);                                 \
  } while (0)

// ---- prep: xcast + fragment-major dequants (R7-verified, unchanged) -------
__device__ __forceinline__ void cast8(const float* __restrict__ in,
                                      __bf16* __restrict__ out, size_t idx) {
  f32x4 a = *(const f32x4*)(in + idx);
  f32x4 b = *(const f32x4*)(in + idx + 4);
  bf16x8 o;
#pragma unroll
  for (int i = 0; i < 4; ++i) { o[i] = (__bf16)a[i]; o[i + 4] = (__bf16)b[i]; }
  *(bf16x8*)(out + idx) = o;
}

__global__ void prep(const float* __restrict__ x, const float* __restrict__ wg,
                     const float* __restrict__ sg, const float* __restrict__ wu,
                     const float* __restrict__ su, const float* __restrict__ wd,
                     const float* __restrict__ sd, __bf16* __restrict__ xb,
                     __bf16* __restrict__ wq, __bf16* __restrict__ wdq) {
  int bid = blockIdx.x;
  int tid = threadIdx.x;
  if (bid < 20480) {
    cast8(x, xb, ((size_t)bid * 256 + tid) * 8);
  } else if (bid < 28160) {
    unsigned g = (unsigned)(bid - 20480) * 256u + (unsigned)tid;
    unsigned lane = g & 63u, c = lane & 15u, q = lane >> 4;
    unsigned fr = (g >> 6) & 15u;
    unsigned u = g >> 10;            // bx*160 + t  (< 1920)
    unsigned bx = u / 160u;
    unsigned t = u - bx * 160u;
    unsigned nc = (bx << 8) | (fr << 4) | c;
    unsigned k = (t << 5) | (q << 3);
    unsigned f = nc >> 1;
    const float* wsrc = (nc & 1) ? wu : wg;
    const float* ssrc = (nc & 1) ? su : sg;
    float sc = ssrc[(f >> 7) * 40 + (k >> 7)];
    size_t si = (size_t)f * 5120 + k;
    f32x4 a = *(const f32x4*)(wsrc + si);
    f32x4 b = *(const f32x4*)(wsrc + si + 4);
    bf16x8 o;
#pragma unroll
    for (int i = 0; i < 4; ++i) {
      o[i] = (__bf16)(a[i] * sc);
      o[i + 4] = (__bf16)(b[i] * sc);
    }
    *(bf16x8*)(wq + (size_t)g * 8) = o;
  } else {
    unsigned g = (unsigned)(bid - 28160) * 256u + (unsigned)tid;
    unsigned lane = g & 63u, c = lane & 15u, q = lane >> 4;
    unsigned fr = (g >> 6) & 15u;
    unsigned u = g >> 10;            // bx*48 + t  (< 960)
    unsigned bx = u / 48u;
    unsigned t = u - bx * 48u;
    unsigned nc = (bx << 8) | (fr << 4) | c;
    unsigned k = (t << 5) | (q << 3);
    float sc = sd[(nc >> 7) * 12 + (k >> 7)];
    size_t si = (size_t)nc * 1536 + k;
    f32x4 a = *(const f32x4*)(wd + si);
    f32x4 b = *(const f32x4*)(wd + si + 4);
    bf16x8 o;
#pragma unroll
    for (int i = 0; i < 4; ++i) {
      o[i] = (__bf16)(a[i] * sc);
      o[i + 4] = (__bf16)(b[i] * sc);
    }
    *(bf16x8*)(wdq + (size_t)g * 8) = o;
  }
}

// ---- flatmm GEMM: C = A @ Bfm^T -------------------------------------------
// A:[M,K] bf16 row-major. Bfm: fragment-major weights (see prep).
// Tile 128(M) x 256(N), 4 waves; A ring-3 LDS (16KB super-slots); B in regs.
template <bool FUSE_SILU, typename OutT>
__global__ __launch_bounds__(256, 2) void gemm_p(
    const __bf16* __restrict__ A, const __bf16* __restrict__ Bfm,
    OutT* __restrict__ C, int M, int N, int K, int ldc, int nbx) {
  __shared__ __bf16 lds[3 * 8192];  // 3 ring slots x 16 KB (128 rows x 64 K)
  const int tid = threadIdx.x;
  const int lane = tid & 63;
  const int wave = tid >> 6;
  const int lr = lane & 15;
  const int NT = K >> 5;   // 32-K slices (B layout granularity)
  const int NS = K >> 6;   // 64-K super-steps (80 / 24)

  // bijective XCD-chunked swizzle (gridDim.x % 8 == 0)
  const int nwg = gridDim.x;
  const int lb = (blockIdx.x & 7) * (nwg >> 3) + (blockIdx.x >> 3);
  const int bx = lb % nbx;
  const int by = lb / nbx;
  const int m0 = by * 128, n0 = bx * 256;

  // A-fragment byte offset within 1KB subtile (R4-verified swizzle pair)
  int laneoff = (lr << 6) | ((lane >> 4) << 4);
  laneoff ^= ((lr & 2) << 3) | ((lr & 8) << 2);

  // A staging: 2 chunks/thread per 8KB half-slab, inverse-swizzled source
  int r0, k0, r1, k1;
  chunk_rk(tid, r0, k0);
  chunk_rk(tid + 256, r1, k1);
  const unsigned o0 = (unsigned)r0 * K + (unsigned)k0;
  const unsigned o1 = (unsigned)r1 * K + (unsigned)k1;
  const int d0 = tid << 3, d1 = (tid + 256) << 3;
  const __bf16* Ab = A + (size_t)m0 * K;
  // B fragment base for this wave: frags wave*4 + j, chunk-lane = lane.
  const __bf16* Bf =
      Bfm + ((size_t)bx * NT * 16 + wave * 4) * 512 + (size_t)lane * 8;

  f32x4 acc[8][4] = {};
  bf16x8 af0[4], af1[4];
  u32x4 bgA[4], bgB[4];

  // stage one 64-K super-slot (both 8KB halves): 4 glds
  auto STAGE_A = [&](int t_, int s_) {
    __bf16* lp = lds + s_ * 8192;
#pragma unroll
    for (int ks = 0; ks < 2; ++ks) {
      const unsigned ko = ((unsigned)t_ << 6) | (ks << 5);
      glds16(Ab + (o0 + ko), lp + ks * 4096 + d0);
      glds16(Ab + (o1 + ko), lp + ks * 4096 + d1);
    }
  };

#define RD4(dst_, base_, h_)                                              \
  {                                                                       \
    _Pragma("unroll") for (int i = 0; i < 4; ++i) dst_[i] =               \
        *(const bf16x8*)((base_) + ((((h_) << 2) + i) << 10) + laneoff);  \
  }

#define MFMA16(h_, af_, bk_)                                              \
  {                                                                       \
    __builtin_amdgcn_s_setprio(1);                                        \
    _Pragma("unroll") for (int j = 0; j < 4; ++j) {                       \
      bf16x8 b_ = __builtin_bit_cast(bf16x8, bk_[j]);                     \
      _Pragma("unroll") for (int i = 0; i < 4; ++i)                       \
          acc[((h_) << 2) + i][j] = __builtin_amdgcn_mfma_f32_16x16x32_bf16( \
              af_[i], b_, acc[((h_) << 2) + i][j], 0, 0, 0);              \
    }                                                                     \
    __builtin_amdgcn_s_setprio(0);                                        \
  }

#define B_LOAD(t32_, B_)                                                     \
  {                                                                          \
    const __bf16* bp = Bf + (size_t)(t32_) * 8192;                           \
    asm volatile("global_load_dwordx4 %0, %1, off" : "=v"(B_[0]) : "v"(bp)); \
    asm volatile("global_load_dwordx4 %0, %1, off offset:1024"               \
                 : "=v"(B_[1]) : "v"(bp));                                   \
    asm volatile("global_load_dwordx4 %0, %1, off offset:2048"               \
                 : "=v"(B_[2]) : "v"(bp));                                   \
    asm volatile("global_load_dwordx4 %0, %1, off offset:3072"               \
                 : "=v"(B_[3]) : "v"(bp));                                   \
  }

  // prologue: issue [A(0)4, B(0,a)4, B(0,b)4, A(1)4]; wait-to-4 leaves A(1).
  STAGE_A(0, 0);
  B_LOAD(0, bgA);
  B_LOAD(1, bgB);
  STAGE_A(1, 1);
  VMBAR(4);

  int cur = 0, stg = 2;
  for (int t = 0; t < NS; ++t) {
    const char* cb = (const char*)lds + cur * 16384;
    int tn = t + 2; if (tn > NS - 1) tn = NS - 1;  // uniform clamped tail
    int tb = t + 1; if (tb > NS - 1) tb = NS - 1;
    // ---- half a (k 0..31 of super): af0/af1 pipelined, bgA ----
    RD4(af0, cb, 0);
    RD4(af1, cb, 1);
    LGKMC(4);            // af0 ready; af1 lands under MFMA
    MFMA16(0, af0, bgA);
    LGKMC(0);
    RD4(af0, cb + 8192, 0);     // half b reads issued under MFMA
    MFMA16(1, af1, bgA);
    B_LOAD(2 * tb, bgA);        // B(t+1, a) -- after last bgA consumer
    RD4(af1, cb + 8192, 1);
    // ---- half b (k 32..63): bgB ----
    LGKMC(4);            // af0 (half b) ready
    MFMA16(0, af0, bgB);
    LGKMC(0);
    MFMA16(1, af1, bgB);
    B_LOAD(2 * tb + 1, bgB);    // B(t+1, b)
    STAGE_A(tn, stg);           // A(t+2)
    VMBAR(4);                   // drain A(t+1)+... -> next super ready
    cur = (cur == 2) ? 0 : cur + 1;
    stg = (stg == 2) ? 0 : stg + 1;
  }
  VMBAR(0);  // drain redundant tail loads before epilogue/exit
#undef RD4
#undef MFMA16
#undef B_LOAD

  // C/D layout (m89-verified): col = lane&15, row = (lane>>4)*4 + reg.
  const int colb = n0 + (wave << 6) + lr;
  const int rowb = m0 + ((lane >> 4) << 2);
#pragma unroll
  for (int i = 0; i < 8; ++i)
#pragma unroll
    for (int j = 0; j < 4; ++j)
#pragma unroll
      for (int r = 0; r < 4; ++r) {
        if constexpr (FUSE_SILU) {
          // lanes (2k,2k+1) hold cols (gate_f, up_f) of the same row.
          float v = acc[i][j][r];
          float p = __shfl_xor(v, 1, 64);
          float g = (lane & 1) ? p : v;
          float u = (lane & 1) ? v : p;
          float hv = (g / (1.0f + __expf(-g))) * u;
          if ((lane & 1) == 0)
            C[(size_t)(rowb + i * 16 + r) * ldc + ((colb + j * 16) >> 1)] =
                (OutT)hv;
        } else {
          C[(size_t)(rowb + i * 16 + r) * ldc + (colb + j * 16)] =
              (OutT)acc[i][j][r];
        }
      }
}

extern "C" void kernel_launch(void* const* d_in, const int* in_sizes, int n_in,
                              void* d_out, int out_size, void* d_ws,
                              size_t ws_size, hipStream_t stream) {
  const int Hd = 5120, Fd = 1536, Td = 8192;
  const float* x = (const float*)d_in[0];
  const float* wg = (const float*)d_in[1];
  const float* sg = (const float*)d_in[2];
  const float* wu = (const float*)d_in[3];
  const float* su = (const float*)d_in[4];
  const float* wd = (const float*)d_in[5];
  const float* sd = (const float*)d_in[6];
  float* out = (float*)d_out;

  // ws layout (bf16): xb [T*H] | wqf [2F*H] | wdqf [H*F] | h [T*F]  ~156 MB
  __bf16* ws = (__bf16*)d_ws;
  const size_t xsz = (size_t)Td * Hd;
  __bf16* xb = ws;
  __bf16* wqf = xb + xsz;
  __bf16* wdqf = wqf + (size_t)2 * Fd * Hd;
  __bf16* hbuf = wdqf + (size_t)Hd * Fd;

  prep<<<32000, 256, 0, stream>>>(x, wg, sg, wu, su, wd, sd, xb, wqf, wdqf);

  // gemm1: [8192 x 3072] = xb @ wq^T, silu-pair epilogue -> h [8192][1536]
  // grid = (8192/128) * (3072/256) = 64 * 12 = 768 (%8==0); 2 blk/CU
  gemm_p<true, __bf16><<<768, 256, 0, stream>>>(xb, wqf, hbuf, Td, 2 * Fd, Hd,
                                                Fd, 12);

  // gemm2: [8192 x 5120] = h @ wdq^T -> out f32
  // grid = 64 * 20 = 1280 (%8==0); 2 blk/CU
  gemm_p<false, float><<<1280, 256, 0, stream>>>(hbuf, wdqf, out, Td, Hd, Fd,
                                                 Hd, 20);
}